// Round 9
// baseline (186.333 us; speedup 1.0000x reference)
//
#include <hip/hip_runtime.h>
#include <stdint.h>

// Problem constants (fixed by the reference setup):
//   logits (2,4,128,128,128) fp32, target one-hot same shape.
#define NVOX (1u << 21)            // 128^3 voxels per batch (exactly 2^21)
#define NB   2                     // batches
#define KSEL 419430u               // int(0.2 * 2^21)
#define TPB  256
#define VPB  2048                  // voxels per A-block
#define BPB  ((int)(NVOX / VPB))   // 1024 A-blocks per batch
#define ABLK (NB * BPB)            // 2048 A-blocks
#define BBLK 1024                  // B-blocks (512 per batch, 4096 codes each)
#define CPBB 4096                  // codes per B-block
#define WLO  960u                  // histogram window: bins [960, 1216)
#define WN   256                   // window size; bin = fp32_bits >> 20
#define FIXS 262144.0f             // 2^18 fixed-point scale for packed bin sums

typedef unsigned long long u64;

__device__ __forceinline__ float wred64(float v) {
#pragma unroll
  for (int o = 32; o > 0; o >>= 1) v += __shfl_down(v, o, 64);
  return v;
}

// ---- Kernel A: pure streaming. CE per voxel -> u16 code (fp32 bits >> 15:
// exp8+mant8, order-monotone since CE >= 0); dice partial sums. No LDS
// histogram, no atomics of any kind.
__global__ __launch_bounds__(TPB, 4) void kA_ce_dice(
    const float* __restrict__ logits, const float* __restrict__ target,
    uint16_t* __restrict__ codes /* [NB][NVOX] */,
    float* __restrict__ dice /* [ABLK][12] */)
{
  __shared__ float dsh[4][12];
  const int tid = threadIdx.x;
  const int blk = blockIdx.x;
  const int b = blk / BPB;
  const size_t v0 = (size_t)(blk % BPB) * VPB;
  const float* lg = logits + (size_t)b * 4 * NVOX + v0;
  const float* tg = target + (size_t)b * 4 * NVOX + v0;
  uint16_t* cb = codes + (size_t)b * NVOX + v0;

  float sp[4] = {0.f,0.f,0.f,0.f}, nm[4] = {0.f,0.f,0.f,0.f}, ct[4] = {0.f,0.f,0.f,0.f};

#pragma unroll
  for (int i = tid * 4; i < VPB; i += TPB * 4) {
    float4 L[4], T[4];
#pragma unroll
    for (int c = 0; c < 4; ++c) {
      L[c] = *(const float4*)(lg + (size_t)c * NVOX + i);
      T[c] = *(const float4*)(tg + (size_t)c * NVOX + i);
    }
    ushort4 out;
    uint16_t* op = (uint16_t*)&out;
#pragma unroll
    for (int j = 0; j < 4; ++j) {
      float l[4], t[4];
#pragma unroll
      for (int c = 0; c < 4; ++c) {
        l[c] = ((const float*)&L[c])[j];
        t[c] = ((const float*)&T[c])[j];
      }
      float m = fmaxf(fmaxf(l[0], l[1]), fmaxf(l[2], l[3]));
      float e[4]; float s = 0.f;
#pragma unroll
      for (int c = 0; c < 4; ++c) { e[c] = __expf(l[c] - m); s += e[c]; }
      float inv = __builtin_amdgcn_rcpf(s);        // approx ok: dice tolerance loose
      float lse = __logf(s);                       // s >= 1 -> lse >= 0
      float ly = l[0]*t[0] + l[1]*t[1] + l[2]*t[2] + l[3]*t[3]; // exact: t one-hot
      float cev = (m - ly) + lse;                  // >= 0 -> bits monotone
      op[j] = (uint16_t)(__float_as_uint(cev) >> 15);
#pragma unroll
      for (int c = 0; c < 4; ++c) {
        float p = e[c] * inv;
        sp[c] += p;
        nm[c] += p * t[c];
        ct[c] += t[c];
      }
    }
    *(ushort4*)(cb + i) = out;                     // 8B coalesced store
  }

  // dice: wave-reduce, combine 4 waves via tiny LDS, plain store 12 floats.
#pragma unroll
  for (int c = 0; c < 4; ++c) { sp[c] = wred64(sp[c]); nm[c] = wred64(nm[c]); ct[c] = wred64(ct[c]); }
  if ((tid & 63) == 0) {
    const int w = tid >> 6;
#pragma unroll
    for (int c = 0; c < 4; ++c) {
      dsh[w][c]     = sp[c];
      dsh[w][4 + c] = nm[c];
      dsh[w][8 + c] = ct[c];
    }
  }
  __syncthreads();
  if (tid < 12)
    dice[(size_t)blk * 12 + tid] = dsh[0][tid] + dsh[1][tid] + dsh[2][tid] + dsh[3][tid];
}

// ---- Kernel B: histogram only. Reads the 8MB code array (L2/L3-hot),
// builds a 256-bin windowed {count,sum} LDS histogram (2 KB), flushes with
// plain stores into a private slot. Isolates the LDS-atomic cost.
__global__ __launch_bounds__(TPB, 4) void kB_hist(
    const uint16_t* __restrict__ codes,
    u64* __restrict__ hist /* [BBLK][WN] */)
{
  __shared__ u64 hb[WN];           // 2 KB
  const int tid = threadIdx.x;
  if (tid < WN) hb[tid] = 0ull;
  __syncthreads();

  const int bc = blockIdx.x;
  const size_t base = (size_t)bc * CPBB;   // [b][chunk]: bc>>9 = batch (contiguous)
  const uint4* p = (const uint4*)(codes + base);

#pragma unroll
  for (int it = 0; it < CPBB / (TPB * 8); ++it) {
    uint4 v = p[it * TPB + tid];           // 8 codes, coalesced 16B
    const uint32_t ws[4] = {v.x, v.y, v.z, v.w};
#pragma unroll
    for (int q = 0; q < 4; ++q) {
#pragma unroll
      for (int h = 0; h < 2; ++h) {
        uint32_t c = (h == 0) ? (ws[q] & 0xFFFFu) : (ws[q] >> 16);
        uint32_t idx = (c >> 5) - WLO;     // bin = fp_bits>>20, windowed
        if (idx < WN) {
          // decoded midpoint of the 8-mantissa-bit code bucket
          float dec = __uint_as_float((c << 15) | 0x4000u);
          // count in bits[63:40]; 2^18 fixed-point sum in bits[39:0]
          u64 pk = (1ull << 40) | (u64)(dec * FIXS);
          atomicAdd(&hb[idx], pk);
        }
        // codes below the window are far below any plausible tie (CE<2^-7):
        // their counts are never read by the top-down scan.
      }
    }
  }
  __syncthreads();
  if (tid < WN) hist[(size_t)bc * WN + tid] = hb[tid];
}

// ---- Exact column-sum of per-block histograms. 8 blocks.
__global__ __launch_bounds__(256) void k_reduce(
    const u64* __restrict__ hist, uint32_t* __restrict__ rcnt,
    float* __restrict__ rsum)
{
  const int e = blockIdx.x;        // batch = e>>2, 64-bin segment = e&3
  const int b = e >> 2;
  const int seg = e & 3;
  const int lane = threadIdx.x & 63;
  const int wave = threadIdx.x >> 6;
  const int bin = seg * 64 + lane;
  const int rows = BBLK / NB;      // 512 B-blocks per batch
  u64 csum = 0, fsum = 0;
  const int r0 = wave * (rows / 4), r1 = r0 + rows / 4;
  for (int r = r0; r < r1; ++r) {
    u64 v = hist[(size_t)(b * rows + r) * WN + bin];  // 64 lanes: coalesced 512B
    csum += v >> 40;
    fsum += v & 0xFFFFFFFFFFull;
  }
  __shared__ u64 sc[4][64], ss[4][64];
  sc[wave][lane] = csum; ss[wave][lane] = fsum;
  __syncthreads();
  if (wave == 0) {
    csum = sc[0][lane] + sc[1][lane] + sc[2][lane] + sc[3][lane];
    fsum = ss[0][lane] + ss[1][lane] + ss[2][lane] + ss[3][lane];
    rcnt[b * WN + bin] = (uint32_t)csum;
    rsum[b * WN + bin] = (float)((double)fsum * (1.0 / 262144.0));
  }
}

// ---- Final: top-down scan for the tie bin; topk_sum = sum of bins above +
// rem * (tie-bin mean + uniform-density correction). Then dice -> scalar.
__global__ __launch_bounds__(256) void k_final(
    const uint32_t* __restrict__ rcnt, const float* __restrict__ rsum,
    const float* __restrict__ dice, float* __restrict__ out)
{
  __shared__ uint32_t shc[WN];
  __shared__ uint32_t sbkt, srem;
  __shared__ float wpart[4];
  __shared__ float ts[NB];
  __shared__ float cpart[4][24];
  const int tid = threadIdx.x;

  for (int b = 0; b < NB; ++b) {
    const uint32_t cnt = rcnt[b * WN + tid];
    const float    sm  = rsum[b * WN + tid];
    shc[tid] = cnt;
    __syncthreads();
    if (tid == 0) {
      uint32_t k = KSEL, cum = 0, rem = 1;
      int bkt = 0;
      for (int i = WN - 1; i >= 0; --i) {
        uint32_t c = shc[i];
        if (cum + c >= k) { bkt = i; rem = k - cum; break; }
        cum += c;
      }
      sbkt = (uint32_t)bkt;
      srem = rem;                  // 1 <= rem <= shc[bkt]
    }
    __syncthreads();
    const int bkt = (int)sbkt;
    float w = (tid > bkt) ? sm : 0.f;   // exact sum of bins above the tie
    w = wred64(w);
    if ((tid & 63) == 0) wpart[tid >> 6] = w;
    __syncthreads();
    if (tid == 0) {
      float cnt_t = (float)shc[bkt];
      float sum_t = rsum[b * WN + bkt];
      float lo = __uint_as_float((WLO + (uint32_t)bkt) << 20);
      float hi = __uint_as_float((WLO + (uint32_t)bkt + 1) << 20);
      float width = hi - lo;
      float avg = sum_t / cnt_t;
      float frac = (float)srem / cnt_t;
      // uniform-density model: mean of the top-rem subset of the tie bin
      float est = avg + (1.f - frac) * 0.5f * width;
      ts[b] = wpart[0] + wpart[1] + wpart[2] + wpart[3] + (float)srem * est;
    }
    __syncthreads();
  }

  // dice: reduce the per-block partials [ABLK][12].
  float a0[12], a1[12];
#pragma unroll
  for (int c = 0; c < 12; ++c) { a0[c] = 0.f; a1[c] = 0.f; }
  for (int r = tid; r < ABLK; r += 256) {
    const float* dp = dice + (size_t)r * 12;
    if (r < BPB) {
#pragma unroll
      for (int c = 0; c < 12; ++c) a0[c] += dp[c];
    } else {
#pragma unroll
      for (int c = 0; c < 12; ++c) a1[c] += dp[c];
    }
  }
#pragma unroll
  for (int c = 0; c < 12; ++c) { a0[c] = wred64(a0[c]); a1[c] = wred64(a1[c]); }
  if ((tid & 63) == 0) {
    const int w = tid >> 6;
#pragma unroll
    for (int c = 0; c < 12; ++c) { cpart[w][c] = a0[c]; cpart[w][12 + c] = a1[c]; }
  }
  __syncthreads();
  if (tid == 0) {
    float comp[24];
#pragma unroll
    for (int c = 0; c < 24; ++c)
      comp[c] = cpart[0][c] + cpart[1][c] + cpart[2][c] + cpart[3][c];
    float dl = 0.f;
#pragma unroll
    for (int b = 0; b < 2; ++b)
#pragma unroll
      for (int c = 1; c < 4; ++c) {
        float sp = comp[b * 12 + c];
        float nm = comp[b * 12 + 4 + c];
        float ct = comp[b * 12 + 8 + c];
        dl += 1.f - (2.f * nm) / (sp + ct + 1e-6f);
      }
    float topk = 0.5f * (ts[0] + ts[1]) / (float)KSEL;
    out[0] = topk + 0.5f * (dl / 6.f);
  }
}

extern "C" void kernel_launch(void* const* d_in, const int* in_sizes, int n_in,
                              void* d_out, int out_size, void* d_ws, size_t ws_size,
                              hipStream_t stream) {
  (void)in_sizes; (void)n_in; (void)out_size; (void)ws_size;
  const float* logits = (const float*)d_in[0];
  const float* target = (const float*)d_in[1];
  float* out = (float*)d_out;

  // Workspace — every byte fully overwritten each call (poison-safe, no memset):
  //   [hist 2MB][codes 8MB][dice 96KB][rcnt 1KB][rsum 1KB]
  char* ws = (char*)d_ws;
  u64*      hist  = (u64*)ws;                               // BBLK*WN
  uint16_t* codes = (uint16_t*)(hist + (size_t)BBLK * WN);  // NB*NVOX
  float*    dice  = (float*)(codes + (size_t)NB * NVOX);    // ABLK*12
  uint32_t* rcnt  = (uint32_t*)(dice + (size_t)ABLK * 12);  // NB*WN
  float*    rsum  = (float*)(rcnt + NB * WN);               // NB*WN

  kA_ce_dice<<<ABLK, TPB, 0, stream>>>(logits, target, codes, dice);
  kB_hist<<<BBLK, TPB, 0, stream>>>(codes, hist);
  k_reduce<<<8, 256, 0, stream>>>(hist, rcnt, rsum);
  k_final<<<1, 256, 0, stream>>>(rcnt, rsum, dice, out);
}